// Round 6
// baseline (315.407 us; speedup 1.0000x reference)
//
#include <hip/hip_runtime.h>
#include <hip/hip_bf16.h>

#define D 128

typedef __bf16 bf16x8 __attribute__((ext_vector_type(8)));
typedef float f32x16 __attribute__((ext_vector_type(16)));
typedef unsigned ue4 __attribute__((ext_vector_type(4)));
typedef unsigned ue2 __attribute__((ext_vector_type(2)));
typedef float fe4 __attribute__((ext_vector_type(4)));

union U16 { uint4 u; bf16x8 v; };

static __device__ __forceinline__ unsigned short f2bf(float f) {
    unsigned u = __float_as_uint(f);
    unsigned r = (u + 0x7fffu + ((u >> 16) & 1u)) >> 16;   // RNE
    return (unsigned short)r;
}
static __device__ __forceinline__ float bf2f(unsigned short s) {
    return __uint_as_float(((unsigned)s) << 16);
}
static __device__ __forceinline__ float u2f_lo(unsigned x) { return __uint_as_float(x << 16); }
static __device__ __forceinline__ float u2f_hi(unsigned x) { return __uint_as_float(x & 0xffff0000u); }

// ---- non-temporal access helpers (read-once / write-once streams; keep L2 for h rows)
static __device__ __forceinline__ uint4 nt_load_u4(const unsigned* p) {
    ue4 v = __builtin_nontemporal_load((const ue4*)p);
    return make_uint4(v.x, v.y, v.z, v.w);
}
static __device__ __forceinline__ uint2 nt_load_u2(const unsigned* p) {
    ue2 v = __builtin_nontemporal_load((const ue2*)p);
    return make_uint2(v.x, v.y);
}
static __device__ __forceinline__ float4 nt_load_f4(const float* p) {
    fe4 v = __builtin_nontemporal_load((const fe4*)p);
    return make_float4(v.x, v.y, v.z, v.w);
}
static __device__ __forceinline__ void nt_store_f4(float4 o, float* p) {
    fe4 v = {o.x, o.y, o.z, o.w};
    __builtin_nontemporal_store(v, (fe4*)p);
}
static __device__ __forceinline__ void nt_store_f(float o, float* p) {
    __builtin_nontemporal_store(o, p);
}

// ===================== fused weight prep (3 matrices) + cnt zero =====================
__global__ __launch_bounds__(256) void k_prep(
        const float* __restrict__ W1, const float* __restrict__ W2, const float* __restrict__ Wf,
        unsigned short* __restrict__ W1h, unsigned short* __restrict__ W1l,
        unsigned short* __restrict__ W2h, unsigned short* __restrict__ W2l,
        unsigned short* __restrict__ Wfh, unsigned short* __restrict__ Wfl,
        int* __restrict__ cnt, int n) {
    int idx = blockIdx.x * 256 + threadIdx.x;
    if (idx < 3 * 16384) {
        int which = idx >> 14;
        int local = idx & 16383;
        int k = local >> 7, c = local & 127;
        const float* W = (which == 0) ? W1 : (which == 1) ? W2 : Wf;
        unsigned short* Wh = (which == 0) ? W1h : (which == 1) ? W2h : Wfh;
        unsigned short* Wl = (which == 0) ? W1l : (which == 1) ? W2l : Wfl;
        float v = W[k * 128 + c];
        unsigned short h = f2bf(v);
        unsigned short l = f2bf(v - bf2f(h));
        Wh[c * 128 + k] = h;
        Wl[c * 128 + k] = l;
    }
    if (idx < n) cnt[idx] = 0;
}

// ===================== CSR build (counting sort by dst) =====================

__global__ __launch_bounds__(256) void k_hist(const int* __restrict__ dst,
                                              int* __restrict__ cnt, int e) {
    int i = blockIdx.x * 256 + threadIdx.x;
    if (i < e) atomicAdd(&cnt[dst[i]], 1);
}

#define SCAN_CHUNK 1024

__global__ __launch_bounds__(256) void k_scan_local(const int* __restrict__ cnt,
                                                    int* __restrict__ ptr,
                                                    int* __restrict__ sums, int n) {
    __shared__ int tsum[256];
    const int t = threadIdx.x;
    const int base = blockIdx.x * SCAN_CHUNK + t * 4;
    int v[4]; int s = 0;
    #pragma unroll
    for (int i = 0; i < 4; ++i) {
        int idx = base + i;
        v[i] = (idx < n) ? cnt[idx] : 0;
        s += v[i];
    }
    tsum[t] = s;
    __syncthreads();
    for (int off = 1; off < 256; off <<= 1) {
        int x = (t >= off) ? tsum[t - off] : 0;
        __syncthreads();
        tsum[t] += x;
        __syncthreads();
    }
    int run = (t > 0) ? tsum[t - 1] : 0;
    if (t == 255) sums[blockIdx.x] = tsum[255];
    #pragma unroll
    for (int i = 0; i < 4; ++i) {
        int idx = base + i;
        if (idx < n) ptr[idx] = run;
        run += v[i];
    }
}

__global__ __launch_bounds__(256) void k_scan_sums(int* __restrict__ sums, int nChunks) {
    __shared__ int ls[256];
    const int t = threadIdx.x;
    ls[t] = (t < nChunks) ? sums[t] : 0;
    __syncthreads();
    for (int off = 1; off < 256; off <<= 1) {
        int x = (t >= off) ? ls[t - off] : 0;
        __syncthreads();
        ls[t] += x;
        __syncthreads();
    }
    if (t < nChunks) sums[t] = (t > 0) ? ls[t - 1] : 0;
}

__global__ __launch_bounds__(256) void k_scan_add(int* __restrict__ ptr,
                                                  const int* __restrict__ sums,
                                                  int* __restrict__ cnt,
                                                  float* __restrict__ dinv,
                                                  int n, int e) {
    int i = blockIdx.x * 256 + threadIdx.x;
    if (i < n) {
        ptr[i] += sums[i >> 10];
        dinv[i] = rsqrtf((float)(1 + cnt[i]));
        cnt[i] = 0;
    }
    if (i == 0) ptr[n] = e;
}

// store {src, dinv[src]} per edge
__global__ __launch_bounds__(256) void k_fill(const int* __restrict__ src,
                                              const int* __restrict__ dst,
                                              const int* __restrict__ ptr,
                                              int* __restrict__ fill,
                                              const float* __restrict__ dinv,
                                              uint2* __restrict__ csr, int e) {
    int i = blockIdx.x * 256 + threadIdx.x;
    if (i < e) {
        int d = dst[i];
        int s = src[i];
        int slot = ptr[d] + atomicAdd(&fill[d], 1);
        csr[slot] = make_uint2((unsigned)s, __float_as_uint(dinv[s]));
    }
}

// ========== dual-output split-bf16 MFMA GEMM, 8 waves, double-buffered LDS ======
// wave w: sel = w>>2 picks {out1/B1, out2/B2}; (w&3) picks the 32-col block.
// out1 = bf16(A@B1); out2 = A@B2 + bias2 (fp32, nt).
#define APAD 136   // 128 + 8 bf16 pad: 272 B stride, 16B-aligned

__global__ __launch_bounds__(512, 4) void k_gemm_dual(
        const float* __restrict__ A,
        const unsigned short* __restrict__ B1h, const unsigned short* __restrict__ B1l,
        const unsigned short* __restrict__ B2h, const unsigned short* __restrict__ B2l,
        const float* __restrict__ bias2,
        unsigned short* __restrict__ out1,
        float* __restrict__ out2,
        int M, int nTiles) {
    __shared__ __align__(16) unsigned short As[2][2][32][APAD];  // [buf][hi/lo][r][c]

    const int tid = threadIdx.x;
    const int wave = tid >> 6;          // 0..7
    const int lane = tid & 63;
    const int l31 = lane & 31;
    const int quad8 = (lane >> 5) * 8;
    const int col = (wave & 3) * 32 + l31;
    const int sel = wave >> 2;          // 0: out1, 1: out2

    const unsigned short* __restrict__ Bh = sel ? B2h : B1h;
    const unsigned short* __restrict__ Bl = sel ? B2l : B1l;

    U16 bh[8], bl[8];
    #pragma unroll
    for (int ks = 0; ks < 8; ++ks) {
        const size_t bo = (size_t)col * D + ks * 16 + quad8;
        bh[ks].u = *(const uint4*)(Bh + bo);
        bl[ks].u = *(const uint4*)(Bl + bo);
    }
    const float bv = bias2[col];

    // per-thread fixed staging coordinates (2 float4 over [32][32])
    const int r0 = tid >> 5;            // 0..15
    const int c0 = (tid & 31) * 4;
    const int r1 = r0 + 16;             // 16..31

    int t = blockIdx.x;
    float4 v0, v1;
    if (t < nTiles) {
        int rg0 = t * 32 + r0; if (rg0 >= M) rg0 = M - 1;
        int rg1 = t * 32 + r1; if (rg1 >= M) rg1 = M - 1;
        v0 = nt_load_f4(A + (size_t)rg0 * D + c0);   // x is read-once: nt
        v1 = nt_load_f4(A + (size_t)rg1 * D + c0);
    }
    int cur = 0;

    while (t < nTiles) {
        const int row0 = t * 32;

        // convert current regs -> LDS[cur]
        {
            ushort4 hq, lq;
            hq.x = f2bf(v0.x); hq.y = f2bf(v0.y); hq.z = f2bf(v0.z); hq.w = f2bf(v0.w);
            lq.x = f2bf(v0.x - bf2f(hq.x)); lq.y = f2bf(v0.y - bf2f(hq.y));
            lq.z = f2bf(v0.z - bf2f(hq.z)); lq.w = f2bf(v0.w - bf2f(hq.w));
            *(ushort4*)&As[cur][0][r0][c0] = hq;
            *(ushort4*)&As[cur][1][r0][c0] = lq;
            hq.x = f2bf(v1.x); hq.y = f2bf(v1.y); hq.z = f2bf(v1.z); hq.w = f2bf(v1.w);
            lq.x = f2bf(v1.x - bf2f(hq.x)); lq.y = f2bf(v1.y - bf2f(hq.y));
            lq.z = f2bf(v1.z - bf2f(hq.z)); lq.w = f2bf(v1.w - bf2f(hq.w));
            *(ushort4*)&As[cur][0][r1][c0] = hq;
            *(ushort4*)&As[cur][1][r1][c0] = lq;
        }

        // issue next tile's loads (latency hides under MFMA + stores)
        const int tn = t + gridDim.x;
        if (tn < nTiles) {
            int rg0 = tn * 32 + r0; if (rg0 >= M) rg0 = M - 1;
            int rg1 = tn * 32 + r1; if (rg1 >= M) rg1 = M - 1;
            v0 = nt_load_f4(A + (size_t)rg0 * D + c0);
            v1 = nt_load_f4(A + (size_t)rg1 * D + c0);
        }

        __syncthreads();

        f32x16 acc;
        #pragma unroll
        for (int r = 0; r < 16; ++r) acc[r] = 0.f;

        #pragma unroll
        for (int ks = 0; ks < 8; ++ks) {
            U16 ah, al;
            ah.u = *(const uint4*)&As[cur][0][l31][ks * 16 + quad8];
            al.u = *(const uint4*)&As[cur][1][l31][ks * 16 + quad8];
            acc = __builtin_amdgcn_mfma_f32_32x32x16_bf16(ah.v, bh[ks].v, acc, 0, 0, 0);
            acc = __builtin_amdgcn_mfma_f32_32x32x16_bf16(ah.v, bl[ks].v, acc, 0, 0, 0);
            acc = __builtin_amdgcn_mfma_f32_32x32x16_bf16(al.v, bh[ks].v, acc, 0, 0, 0);
        }

        if (sel == 0) {
            #pragma unroll
            for (int reg = 0; reg < 16; ++reg) {
                const int r = (reg & 3) + 8 * (reg >> 2) + 4 * (lane >> 5);
                const int rg = row0 + r;
                if (rg < M) out1[(size_t)rg * D + col] = f2bf(acc[reg]);  // h: keep cached
            }
        } else {
            #pragma unroll
            for (int reg = 0; reg < 16; ++reg) {
                const int r = (reg & 3) + 8 * (reg >> 2) + 4 * (lane >> 5);
                const int rg = row0 + r;
                if (rg < M) nt_store_f(acc[reg] + bv, out2 + (size_t)rg * D + col);
            }
        }

        cur ^= 1;
        t = tn;
    }
}

// ========== fused aggregate(layer1) + GEMM(W2): h2 = bf16(relu(A h + b1) @ W2) ==
__global__ __launch_bounds__(256, 4) void k_agg_gemm(
        const int* __restrict__ ptr,
        const uint2* __restrict__ csr,
        const float* __restrict__ dinv,
        const unsigned short* __restrict__ h,
        const float* __restrict__ bias,
        const unsigned short* __restrict__ Bh, const unsigned short* __restrict__ Bl,
        unsigned short* __restrict__ outb,
        int M, int nTiles) {
    __shared__ __align__(16) unsigned short As[32][APAD];

    const int tid = threadIdx.x;
    const int wave = tid >> 6;
    const int lane64 = tid & 63;
    const int l31 = lane64 & 31;
    const int quad8 = (lane64 >> 5) * 8;
    const int col = wave * 32 + l31;

    const int g = tid >> 5;             // 0..7 aggregation group
    const int lane = tid & 31;

    U16 bh[8], bl[8];
    #pragma unroll
    for (int ks = 0; ks < 8; ++ks) {
        const size_t bo = (size_t)col * D + ks * 16 + quad8;
        bh[ks].u = *(const uint4*)(Bh + bo);
        bl[ks].u = *(const uint4*)(Bl + bo);
    }
    const float4 bvv = *(const float4*)(bias + lane * 4);
    const unsigned* cb = (const unsigned*)csr;

    for (int t = blockIdx.x; t < nTiles; t += gridDim.x) {
        const int row0 = t * 32;

        // ---- phase 1: aggregate rows g*4 .. g*4+3 into LDS ----
        for (int rr = 0; rr < 4; ++rr) {
            const int r = g * 4 + rr;
            int ig = row0 + r; if (ig >= M) ig = M - 1;
            const int p0 = ptr[ig];
            const int p1 = ptr[ig + 1];
            const float di = dinv[ig];
            const uint2 us = *(const uint2*)(h + (size_t)ig * D + lane * 4);

            float a0 = 0.f, a1 = 0.f, a2 = 0.f, a3 = 0.f;
            int j = p0;
            for (; j + 4 <= p1; j += 4) {
                const uint4 e0 = nt_load_u4(cb + 2 * (size_t)j);
                const uint4 e1 = nt_load_u4(cb + 2 * (size_t)j + 4);
                const float c0 = __uint_as_float(e0.y);
                const float c1 = __uint_as_float(e0.w);
                const float c2 = __uint_as_float(e1.y);
                const float c3 = __uint_as_float(e1.w);
                const uint2 u0 = *(const uint2*)(h + (size_t)e0.x * D + lane * 4);
                const uint2 u1 = *(const uint2*)(h + (size_t)e0.z * D + lane * 4);
                const uint2 u2 = *(const uint2*)(h + (size_t)e1.x * D + lane * 4);
                const uint2 u3 = *(const uint2*)(h + (size_t)e1.z * D + lane * 4);
                a0 = fmaf(c0, u2f_lo(u0.x), a0); a1 = fmaf(c0, u2f_hi(u0.x), a1);
                a2 = fmaf(c0, u2f_lo(u0.y), a2); a3 = fmaf(c0, u2f_hi(u0.y), a3);
                a0 = fmaf(c1, u2f_lo(u1.x), a0); a1 = fmaf(c1, u2f_hi(u1.x), a1);
                a2 = fmaf(c1, u2f_lo(u1.y), a2); a3 = fmaf(c1, u2f_hi(u1.y), a3);
                a0 = fmaf(c2, u2f_lo(u2.x), a0); a1 = fmaf(c2, u2f_hi(u2.x), a1);
                a2 = fmaf(c2, u2f_lo(u2.y), a2); a3 = fmaf(c2, u2f_hi(u2.y), a3);
                a0 = fmaf(c3, u2f_lo(u3.x), a0); a1 = fmaf(c3, u2f_hi(u3.x), a1);
                a2 = fmaf(c3, u2f_lo(u3.y), a2); a3 = fmaf(c3, u2f_hi(u3.y), a3);
            }
            const int rem = p1 - j;
            if (rem > 0) {
                const int j1 = (rem > 1) ? j + 1 : j;
                const int j2 = (rem > 2) ? j + 2 : j;
                const uint2 e0 = nt_load_u2(cb + 2 * (size_t)j);
                const uint2 e1 = nt_load_u2(cb + 2 * (size_t)j1);
                const uint2 e2 = nt_load_u2(cb + 2 * (size_t)j2);
                const float c0 = __uint_as_float(e0.y);
                const float c1 = (rem > 1) ? __uint_as_float(e1.y) : 0.f;
                const float c2 = (rem > 2) ? __uint_as_float(e2.y) : 0.f;
                const uint2 u0 = *(const uint2*)(h + (size_t)e0.x * D + lane * 4);
                const uint2 u1 = *(const uint2*)(h + (size_t)e1.x * D + lane * 4);
                const uint2 u2 = *(const uint2*)(h + (size_t)e2.x * D + lane * 4);
                a0 = fmaf(c0, u2f_lo(u0.x), a0); a1 = fmaf(c0, u2f_hi(u0.x), a1);
                a2 = fmaf(c0, u2f_lo(u0.y), a2); a3 = fmaf(c0, u2f_hi(u0.y), a3);
                a0 = fmaf(c1, u2f_lo(u1.x), a0); a1 = fmaf(c1, u2f_hi(u1.x), a1);
                a2 = fmaf(c1, u2f_lo(u1.y), a2); a3 = fmaf(c1, u2f_hi(u1.y), a3);
                a0 = fmaf(c2, u2f_lo(u2.x), a0); a1 = fmaf(c2, u2f_hi(u2.x), a1);
                a2 = fmaf(c2, u2f_lo(u2.y), a2); a3 = fmaf(c2, u2f_hi(u2.y), a3);
            }

            const float self = di * di;
            const float o0 = fmaxf(di * a0 + self * u2f_lo(us.x) + bvv.x, 0.0f);
            const float o1 = fmaxf(di * a1 + self * u2f_hi(us.x) + bvv.y, 0.0f);
            const float o2 = fmaxf(di * a2 + self * u2f_lo(us.y) + bvv.z, 0.0f);
            const float o3 = fmaxf(di * a3 + self * u2f_hi(us.y) + bvv.w, 0.0f);
            ushort4 q = {f2bf(o0), f2bf(o1), f2bf(o2), f2bf(o3)};
            *(ushort4*)&As[r][lane * 4] = q;
        }
        __syncthreads();

        // ---- phase 2: GEMM with W2 ----
        f32x16 acc;
        #pragma unroll
        for (int r = 0; r < 16; ++r) acc[r] = 0.f;

        #pragma unroll
        for (int ks = 0; ks < 8; ++ks) {
            U16 ah;
            ah.u = *(const uint4*)&As[l31][ks * 16 + quad8];
            acc = __builtin_amdgcn_mfma_f32_32x32x16_bf16(ah.v, bh[ks].v, acc, 0, 0, 0);
            acc = __builtin_amdgcn_mfma_f32_32x32x16_bf16(ah.v, bl[ks].v, acc, 0, 0, 0);
        }
        __syncthreads();

        #pragma unroll
        for (int reg = 0; reg < 16; ++reg) {
            const int r = (reg & 3) + 8 * (reg >> 2) + 4 * (lane64 >> 5);
            const int rg = row0 + r;
            if (rg < M) outb[(size_t)rg * D + col] = f2bf(acc[reg]);  // h2: keep cached
        }
    }
}

// ============ fused gather (bf16 h), 32-lane group/node, weights inline =========
__global__ __launch_bounds__(256) void k_gather_w(const int* __restrict__ ptr,
                                                  const uint2* __restrict__ csr,
                                                  const float* __restrict__ dinv,
                                                  const unsigned short* __restrict__ h,
                                                  const float* __restrict__ bias,
                                                  const float* __restrict__ res,
                                                  float* __restrict__ outf,
                                                  unsigned short* __restrict__ outb,
                                                  int N) {
    const int g = threadIdx.x >> 5;
    const int lane = threadIdx.x & 31;
    const int i = blockIdx.x * 8 + g;
    if (i >= N) return;

    const int p0 = ptr[i];
    const int p1 = ptr[i + 1];
    const float di = dinv[i];

    const uint2 us = *(const uint2*)(h + (size_t)i * D + lane * 4);
    const float4 bvv = *(const float4*)(bias + lane * 4);

    float a0 = 0.f, a1 = 0.f, a2 = 0.f, a3 = 0.f;
    const unsigned* cb = (const unsigned*)csr;
    int j = p0;
    for (; j + 4 <= p1; j += 4) {
        const uint4 e0 = nt_load_u4(cb + 2 * (size_t)j);
        const uint4 e1 = nt_load_u4(cb + 2 * (size_t)j + 4);
        const float c0 = __uint_as_float(e0.y);
        const float c1 = __uint_as_float(e0.w);
        const float c2 = __uint_as_float(e1.y);
        const float c3 = __uint_as_float(e1.w);
        const uint2 u0 = *(const uint2*)(h + (size_t)e0.x * D + lane * 4);
        const uint2 u1 = *(const uint2*)(h + (size_t)e0.z * D + lane * 4);
        const uint2 u2 = *(const uint2*)(h + (size_t)e1.x * D + lane * 4);
        const uint2 u3 = *(const uint2*)(h + (size_t)e1.z * D + lane * 4);
        a0 = fmaf(c0, u2f_lo(u0.x), a0); a1 = fmaf(c0, u2f_hi(u0.x), a1);
        a2 = fmaf(c0, u2f_lo(u0.y), a2); a3 = fmaf(c0, u2f_hi(u0.y), a3);
        a0 = fmaf(c1, u2f_lo(u1.x), a0); a1 = fmaf(c1, u2f_hi(u1.x), a1);
        a2 = fmaf(c1, u2f_lo(u1.y), a2); a3 = fmaf(c1, u2f_hi(u1.y), a3);
        a0 = fmaf(c2, u2f_lo(u2.x), a0); a1 = fmaf(c2, u2f_hi(u2.x), a1);
        a2 = fmaf(c2, u2f_lo(u2.y), a2); a3 = fmaf(c2, u2f_hi(u2.y), a3);
        a0 = fmaf(c3, u2f_lo(u3.x), a0); a1 = fmaf(c3, u2f_hi(u3.x), a1);
        a2 = fmaf(c3, u2f_lo(u3.y), a2); a3 = fmaf(c3, u2f_hi(u3.y), a3);
    }
    const int r = p1 - j;
    if (r > 0) {
        const int j1 = (r > 1) ? j + 1 : j;
        const int j2 = (r > 2) ? j + 2 : j;
        const uint2 e0 = nt_load_u2(cb + 2 * (size_t)j);
        const uint2 e1 = nt_load_u2(cb + 2 * (size_t)j1);
        const uint2 e2 = nt_load_u2(cb + 2 * (size_t)j2);
        const float c0 = __uint_as_float(e0.y);
        const float c1 = (r > 1) ? __uint_as_float(e1.y) : 0.f;
        const float c2 = (r > 2) ? __uint_as_float(e2.y) : 0.f;
        const uint2 u0 = *(const uint2*)(h + (size_t)e0.x * D + lane * 4);
        const uint2 u1 = *(const uint2*)(h + (size_t)e1.x * D + lane * 4);
        const uint2 u2 = *(const uint2*)(h + (size_t)e2.x * D + lane * 4);
        a0 = fmaf(c0, u2f_lo(u0.x), a0); a1 = fmaf(c0, u2f_hi(u0.x), a1);
        a2 = fmaf(c0, u2f_lo(u0.y), a2); a3 = fmaf(c0, u2f_hi(u0.y), a3);
        a0 = fmaf(c1, u2f_lo(u1.x), a0); a1 = fmaf(c1, u2f_hi(u1.x), a1);
        a2 = fmaf(c1, u2f_lo(u1.y), a2); a3 = fmaf(c1, u2f_hi(u1.y), a3);
        a0 = fmaf(c2, u2f_lo(u2.x), a0); a1 = fmaf(c2, u2f_hi(u2.x), a1);
        a2 = fmaf(c2, u2f_lo(u2.y), a2); a3 = fmaf(c2, u2f_hi(u2.y), a3);
    }

    const float self = di * di;
    float o0 = fmaxf(di * a0 + self * u2f_lo(us.x) + bvv.x, 0.0f);
    float o1 = fmaxf(di * a1 + self * u2f_hi(us.x) + bvv.y, 0.0f);
    float o2 = fmaxf(di * a2 + self * u2f_lo(us.y) + bvv.z, 0.0f);
    float o3 = fmaxf(di * a3 + self * u2f_hi(us.y) + bvv.w, 0.0f);
    if (outb) {
        ushort4 q = {f2bf(o0), f2bf(o1), f2bf(o2), f2bf(o3)};
        *(ushort4*)(outb + (size_t)i * D + lane * 4) = q;
    } else {
        const float4 rv = nt_load_f4(res + (size_t)i * D + lane * 4);
        float4 o = {o0 + rv.x, o1 + rv.y, o2 + rv.z, o3 + rv.w};
        nt_store_f4(o, outf + (size_t)i * D + lane * 4);
    }
}

// ===================== launch =====================

extern "C" void kernel_launch(void* const* d_in, const int* in_sizes, int n_in,
                              void* d_out, int out_size, void* d_ws, size_t ws_size,
                              hipStream_t stream) {
    const int N = in_sizes[0] / D;     // 100000
    const int E = in_sizes[1] / 2;     // 600000

    const float* x   = (const float*)d_in[0];
    const int*   ei  = (const int*)d_in[1];
    const int*   src = ei;
    const int*   dst = ei + E;
    const float* W1  = (const float*)d_in[2];
    const float* b1  = (const float*)d_in[3];
    const float* W2  = (const float*)d_in[4];
    const float* b2  = (const float*)d_in[5];
    const float* Wfc = (const float*)d_in[6];
    const float* bfc = (const float*)d_in[7];
    float* out = (float*)d_out;

    // ---- workspace layout ----
    char* ws = (char*)d_ws;
    size_t off = 0;
    auto alloc = [&](size_t bytes) { char* p = ws + off; off += (bytes + 255) & ~(size_t)255; return p; };
    float* dinv    = (float*)alloc((size_t)N * 4);
    int*   cnt     = (int*)  alloc((size_t)N * 4);
    int*   ptr     = (int*)  alloc((size_t)(N + 1) * 4);
    int*   sums    = (int*)  alloc(256 * 4);
    uint2* csr     = (uint2*)alloc((size_t)(E + 64) * sizeof(uint2)); // {src, w}
    unsigned short* W1h = (unsigned short*)alloc(128 * 128 * 2);
    unsigned short* W1l = (unsigned short*)alloc(128 * 128 * 2);
    unsigned short* W2h = (unsigned short*)alloc(128 * 128 * 2);
    unsigned short* W2l = (unsigned short*)alloc(128 * 128 * 2);
    unsigned short* Wfh = (unsigned short*)alloc(128 * 128 * 2);
    unsigned short* Wfl = (unsigned short*)alloc(128 * 128 * 2);
    unsigned short* h   = (unsigned short*)alloc((size_t)N * D * 2);  // bf16 x@W1
    unsigned short* h2  = (unsigned short*)alloc((size_t)N * D * 2);  // bf16 layer-2 pre-agg

    const int nBlk    = (N + 255) / 256;
    const int eBlk    = (E + 255) / 256;
    const int aBlk    = (N + 7) / 8;
    const int nChunks = (N + SCAN_CHUNK - 1) / SCAN_CHUNK;
    const int nTiles  = (N + 31) / 32;
    const int gBlk    = nTiles < 1024 ? nTiles : 1024;   // 512-thr dual: 4 blk/CU = 32 waves
    const int aggBlk  = nTiles < 2048 ? nTiles : 2048;   // 256-thr agg: 8 blk/CU = 32 waves
    const int pBlk    = (nBlk > 192) ? nBlk : 192;

    // ---- weight prep + cnt zero (one dispatch) ----
    k_prep<<<pBlk, 256, 0, stream>>>(W1, W2, Wfc, W1h, W1l, W2h, W2l, Wfh, Wfl, cnt, N);

    // ---- CSR build + dinv (weights inline) ----
    k_hist<<<eBlk, 256, 0, stream>>>(dst, cnt, E);
    k_scan_local<<<nChunks, 256, 0, stream>>>(cnt, ptr, sums, N);
    k_scan_sums<<<1, 256, 0, stream>>>(sums, nChunks);
    k_scan_add<<<nBlk, 256, 0, stream>>>(ptr, sums, cnt, dinv, N, E);
    k_fill<<<eBlk, 256, 0, stream>>>(src, dst, ptr, cnt, dinv, csr, E);

    // ---- h = bf16(x@W1) AND out = x@Wfc + bfc, A staged once, dbuf ----
    k_gemm_dual<<<gBlk, 512, 0, stream>>>(x, W1h, W1l, Wfh, Wfl, bfc, h, out, N, nTiles);

    // ---- h2 = bf16( relu(A h + b1) @ W2 )  (fused gather#1 + GEMM2) ----
    k_agg_gemm<<<aggBlk, 256, 0, stream>>>(ptr, csr, dinv, h, b1, W2h, W2l, h2, N, nTiles);

    // ---- layer 2 aggregate + residual -> fp32 out ----
    k_gather_w<<<aBlk, 256, 0, stream>>>(ptr, csr, dinv, h2, b2, out, out, nullptr, N);
}

// Round 7
// 295.664 us; speedup vs baseline: 1.0668x; 1.0668x over previous
//
#include <hip/hip_runtime.h>
#include <hip/hip_bf16.h>

#define D 128

typedef __bf16 bf16x8 __attribute__((ext_vector_type(8)));
typedef float f32x16 __attribute__((ext_vector_type(16)));

union U16 { uint4 u; bf16x8 v; };

static __device__ __forceinline__ unsigned short f2bf(float f) {
    unsigned u = __float_as_uint(f);
    unsigned r = (u + 0x7fffu + ((u >> 16) & 1u)) >> 16;   // RNE
    return (unsigned short)r;
}
static __device__ __forceinline__ float bf2f(unsigned short s) {
    return __uint_as_float(((unsigned)s) << 16);
}
static __device__ __forceinline__ float u2f_lo(unsigned x) { return __uint_as_float(x << 16); }
static __device__ __forceinline__ float u2f_hi(unsigned x) { return __uint_as_float(x & 0xffff0000u); }

// ===================== fused weight prep (3 matrices) + cnt zero =====================
__global__ __launch_bounds__(256) void k_prep(
        const float* __restrict__ W1, const float* __restrict__ W2, const float* __restrict__ Wf,
        unsigned short* __restrict__ W1h, unsigned short* __restrict__ W1l,
        unsigned short* __restrict__ W2h, unsigned short* __restrict__ W2l,
        unsigned short* __restrict__ Wfh, unsigned short* __restrict__ Wfl,
        int* __restrict__ cnt, int n) {
    int idx = blockIdx.x * 256 + threadIdx.x;
    if (idx < 3 * 16384) {
        int which = idx >> 14;
        int local = idx & 16383;
        int k = local >> 7, c = local & 127;
        const float* W = (which == 0) ? W1 : (which == 1) ? W2 : Wf;
        unsigned short* Wh = (which == 0) ? W1h : (which == 1) ? W2h : Wfh;
        unsigned short* Wl = (which == 0) ? W1l : (which == 1) ? W2l : Wfl;
        float v = W[k * 128 + c];
        unsigned short h = f2bf(v);
        unsigned short l = f2bf(v - bf2f(h));
        Wh[c * 128 + k] = h;
        Wl[c * 128 + k] = l;
    }
    if (idx < n) cnt[idx] = 0;
}

// ===================== CSR build (counting sort by dst) =====================

__global__ __launch_bounds__(256) void k_hist(const int* __restrict__ dst,
                                              int* __restrict__ cnt, int e) {
    int i = blockIdx.x * 256 + threadIdx.x;
    if (i < e) atomicAdd(&cnt[dst[i]], 1);
}

#define SCAN_CHUNK 1024

__global__ __launch_bounds__(256) void k_scan_local(const int* __restrict__ cnt,
                                                    int* __restrict__ ptr,
                                                    int* __restrict__ sums, int n) {
    __shared__ int tsum[256];
    const int t = threadIdx.x;
    const int base = blockIdx.x * SCAN_CHUNK + t * 4;
    int v[4]; int s = 0;
    #pragma unroll
    for (int i = 0; i < 4; ++i) {
        int idx = base + i;
        v[i] = (idx < n) ? cnt[idx] : 0;
        s += v[i];
    }
    tsum[t] = s;
    __syncthreads();
    for (int off = 1; off < 256; off <<= 1) {
        int x = (t >= off) ? tsum[t - off] : 0;
        __syncthreads();
        tsum[t] += x;
        __syncthreads();
    }
    int run = (t > 0) ? tsum[t - 1] : 0;
    if (t == 255) sums[blockIdx.x] = tsum[255];
    #pragma unroll
    for (int i = 0; i < 4; ++i) {
        int idx = base + i;
        if (idx < n) ptr[idx] = run;
        run += v[i];
    }
}

__global__ __launch_bounds__(256) void k_scan_sums(int* __restrict__ sums, int nChunks) {
    __shared__ int ls[256];
    const int t = threadIdx.x;
    ls[t] = (t < nChunks) ? sums[t] : 0;
    __syncthreads();
    for (int off = 1; off < 256; off <<= 1) {
        int x = (t >= off) ? ls[t - off] : 0;
        __syncthreads();
        ls[t] += x;
        __syncthreads();
    }
    if (t < nChunks) sums[t] = (t > 0) ? ls[t - 1] : 0;
}

__global__ __launch_bounds__(256) void k_scan_add(int* __restrict__ ptr,
                                                  const int* __restrict__ sums,
                                                  int* __restrict__ cnt,
                                                  float* __restrict__ dinv,
                                                  int n, int e) {
    int i = blockIdx.x * 256 + threadIdx.x;
    if (i < n) {
        ptr[i] += sums[i >> 10];
        dinv[i] = rsqrtf((float)(1 + cnt[i]));
        cnt[i] = 0;
    }
    if (i == 0) ptr[n] = e;
}

// store {src, dinv[src]} per edge
__global__ __launch_bounds__(256) void k_fill(const int* __restrict__ src,
                                              const int* __restrict__ dst,
                                              const int* __restrict__ ptr,
                                              int* __restrict__ fill,
                                              const float* __restrict__ dinv,
                                              uint2* __restrict__ csr, int e) {
    int i = blockIdx.x * 256 + threadIdx.x;
    if (i < e) {
        int d = dst[i];
        int s = src[i];
        int slot = ptr[d] + atomicAdd(&fill[d], 1);
        csr[slot] = make_uint2((unsigned)s, __float_as_uint(dinv[s]));
    }
}

// ========== dual-output GEMM, bf16 A (single plane), split-bf16 B, dbuf LDS =====
// wave w: sel = w>>2 picks {out1/B1, out2/B2}; (w&3) picks the 32-col block.
// out1 = bf16(A@B1); out2 = A@B2 + bias2 (fp32).
// A staged as plain bf16 (matches proven k_gemm_rr_bf numerics); B keeps hi+lo.
#define APAD 136   // 128 + 8 bf16 pad: 272 B stride, 16B-aligned

__global__ __launch_bounds__(512, 4) void k_gemm_dual(
        const float* __restrict__ A,
        const unsigned short* __restrict__ B1h, const unsigned short* __restrict__ B1l,
        const unsigned short* __restrict__ B2h, const unsigned short* __restrict__ B2l,
        const float* __restrict__ bias2,
        unsigned short* __restrict__ out1,
        float* __restrict__ out2,
        int M, int nTiles) {
    __shared__ __align__(16) unsigned short As[2][32][APAD];  // [buf][r][c] bf16

    const int tid = threadIdx.x;
    const int wave = tid >> 6;          // 0..7
    const int lane = tid & 63;
    const int l31 = lane & 31;
    const int quad8 = (lane >> 5) * 8;
    const int col = (wave & 3) * 32 + l31;
    const int sel = wave >> 2;          // 0: out1, 1: out2

    const unsigned short* __restrict__ Bh = sel ? B2h : B1h;
    const unsigned short* __restrict__ Bl = sel ? B2l : B1l;

    U16 bh[8], bl[8];
    #pragma unroll
    for (int ks = 0; ks < 8; ++ks) {
        const size_t bo = (size_t)col * D + ks * 16 + quad8;
        bh[ks].u = *(const uint4*)(Bh + bo);
        bl[ks].u = *(const uint4*)(Bl + bo);
    }
    const float bv = bias2[col];

    // per-thread fixed staging coordinates (2 float4 over [32][32])
    const int r0 = tid >> 5;            // 0..15
    const int c0 = (tid & 31) * 4;
    const int r1 = r0 + 16;             // 16..31

    int t = blockIdx.x;
    float4 v0, v1;
    if (t < nTiles) {
        int rg0 = t * 32 + r0; if (rg0 >= M) rg0 = M - 1;
        int rg1 = t * 32 + r1; if (rg1 >= M) rg1 = M - 1;
        v0 = *(const float4*)(A + (size_t)rg0 * D + c0);
        v1 = *(const float4*)(A + (size_t)rg1 * D + c0);
    }
    int cur = 0;

    while (t < nTiles) {
        const int row0 = t * 32;

        // convert current regs -> LDS[cur] (plain bf16)
        {
            ushort4 hq;
            hq.x = f2bf(v0.x); hq.y = f2bf(v0.y); hq.z = f2bf(v0.z); hq.w = f2bf(v0.w);
            *(ushort4*)&As[cur][r0][c0] = hq;
            hq.x = f2bf(v1.x); hq.y = f2bf(v1.y); hq.z = f2bf(v1.z); hq.w = f2bf(v1.w);
            *(ushort4*)&As[cur][r1][c0] = hq;
        }

        // issue next tile's loads (latency hides under MFMA + stores)
        const int tn = t + gridDim.x;
        if (tn < nTiles) {
            int rg0 = tn * 32 + r0; if (rg0 >= M) rg0 = M - 1;
            int rg1 = tn * 32 + r1; if (rg1 >= M) rg1 = M - 1;
            v0 = *(const float4*)(A + (size_t)rg0 * D + c0);
            v1 = *(const float4*)(A + (size_t)rg1 * D + c0);
        }

        __syncthreads();

        f32x16 acc;
        #pragma unroll
        for (int r = 0; r < 16; ++r) acc[r] = 0.f;

        #pragma unroll
        for (int ks = 0; ks < 8; ++ks) {
            U16 ah;
            ah.u = *(const uint4*)&As[cur][l31][ks * 16 + quad8];
            acc = __builtin_amdgcn_mfma_f32_32x32x16_bf16(ah.v, bh[ks].v, acc, 0, 0, 0);
            acc = __builtin_amdgcn_mfma_f32_32x32x16_bf16(ah.v, bl[ks].v, acc, 0, 0, 0);
        }

        if (sel == 0) {
            #pragma unroll
            for (int reg = 0; reg < 16; ++reg) {
                const int r = (reg & 3) + 8 * (reg >> 2) + 4 * (lane >> 5);
                const int rg = row0 + r;
                if (rg < M) out1[(size_t)rg * D + col] = f2bf(acc[reg]);
            }
        } else {
            #pragma unroll
            for (int reg = 0; reg < 16; ++reg) {
                const int r = (reg & 3) + 8 * (reg >> 2) + 4 * (lane >> 5);
                const int rg = row0 + r;
                if (rg < M) out2[(size_t)rg * D + col] = acc[reg] + bv;
            }
        }

        cur ^= 1;
        t = tn;
    }
}

// ========== fused aggregate(layer1) + GEMM(W2): h2 = bf16(relu(A h + b1) @ W2) ==
__global__ __launch_bounds__(256, 4) void k_agg_gemm(
        const int* __restrict__ ptr,
        const uint2* __restrict__ csr,
        const float* __restrict__ dinv,
        const unsigned short* __restrict__ h,
        const float* __restrict__ bias,
        const unsigned short* __restrict__ Bh, const unsigned short* __restrict__ Bl,
        unsigned short* __restrict__ outb,
        int M, int nTiles) {
    __shared__ __align__(16) unsigned short As[32][APAD];

    const int tid = threadIdx.x;
    const int wave = tid >> 6;
    const int lane64 = tid & 63;
    const int l31 = lane64 & 31;
    const int quad8 = (lane64 >> 5) * 8;
    const int col = wave * 32 + l31;

    const int g = tid >> 5;             // 0..7 aggregation group
    const int lane = tid & 31;

    U16 bh[8], bl[8];
    #pragma unroll
    for (int ks = 0; ks < 8; ++ks) {
        const size_t bo = (size_t)col * D + ks * 16 + quad8;
        bh[ks].u = *(const uint4*)(Bh + bo);
        bl[ks].u = *(const uint4*)(Bl + bo);
    }
    const float4 bvv = *(const float4*)(bias + lane * 4);
    const unsigned* cb = (const unsigned*)csr;

    for (int t = blockIdx.x; t < nTiles; t += gridDim.x) {
        const int row0 = t * 32;

        // ---- phase 1: aggregate rows g*4 .. g*4+3 into LDS ----
        for (int rr = 0; rr < 4; ++rr) {
            const int r = g * 4 + rr;
            int ig = row0 + r; if (ig >= M) ig = M - 1;
            const int p0 = ptr[ig];
            const int p1 = ptr[ig + 1];
            const float di = dinv[ig];
            const uint2 us = *(const uint2*)(h + (size_t)ig * D + lane * 4);

            float a0 = 0.f, a1 = 0.f, a2 = 0.f, a3 = 0.f;
            int j = p0;
            for (; j + 4 <= p1; j += 4) {
                const uint4 e0 = *(const uint4*)(cb + 2 * (size_t)j);
                const uint4 e1 = *(const uint4*)(cb + 2 * (size_t)j + 4);
                const float c0 = __uint_as_float(e0.y);
                const float c1 = __uint_as_float(e0.w);
                const float c2 = __uint_as_float(e1.y);
                const float c3 = __uint_as_float(e1.w);
                const uint2 u0 = *(const uint2*)(h + (size_t)e0.x * D + lane * 4);
                const uint2 u1 = *(const uint2*)(h + (size_t)e0.z * D + lane * 4);
                const uint2 u2 = *(const uint2*)(h + (size_t)e1.x * D + lane * 4);
                const uint2 u3 = *(const uint2*)(h + (size_t)e1.z * D + lane * 4);
                a0 = fmaf(c0, u2f_lo(u0.x), a0); a1 = fmaf(c0, u2f_hi(u0.x), a1);
                a2 = fmaf(c0, u2f_lo(u0.y), a2); a3 = fmaf(c0, u2f_hi(u0.y), a3);
                a0 = fmaf(c1, u2f_lo(u1.x), a0); a1 = fmaf(c1, u2f_hi(u1.x), a1);
                a2 = fmaf(c1, u2f_lo(u1.y), a2); a3 = fmaf(c1, u2f_hi(u1.y), a3);
                a0 = fmaf(c2, u2f_lo(u2.x), a0); a1 = fmaf(c2, u2f_hi(u2.x), a1);
                a2 = fmaf(c2, u2f_lo(u2.y), a2); a3 = fmaf(c2, u2f_hi(u2.y), a3);
                a0 = fmaf(c3, u2f_lo(u3.x), a0); a1 = fmaf(c3, u2f_hi(u3.x), a1);
                a2 = fmaf(c3, u2f_lo(u3.y), a2); a3 = fmaf(c3, u2f_hi(u3.y), a3);
            }
            const int rem = p1 - j;
            if (rem > 0) {
                const int j1 = (rem > 1) ? j + 1 : j;
                const int j2 = (rem > 2) ? j + 2 : j;
                const uint2 e0 = csr[j];
                const uint2 e1 = csr[j1];
                const uint2 e2 = csr[j2];
                const float c0 = __uint_as_float(e0.y);
                const float c1 = (rem > 1) ? __uint_as_float(e1.y) : 0.f;
                const float c2 = (rem > 2) ? __uint_as_float(e2.y) : 0.f;
                const uint2 u0 = *(const uint2*)(h + (size_t)e0.x * D + lane * 4);
                const uint2 u1 = *(const uint2*)(h + (size_t)e1.x * D + lane * 4);
                const uint2 u2 = *(const uint2*)(h + (size_t)e2.x * D + lane * 4);
                a0 = fmaf(c0, u2f_lo(u0.x), a0); a1 = fmaf(c0, u2f_hi(u0.x), a1);
                a2 = fmaf(c0, u2f_lo(u0.y), a2); a3 = fmaf(c0, u2f_hi(u0.y), a3);
                a0 = fmaf(c1, u2f_lo(u1.x), a0); a1 = fmaf(c1, u2f_hi(u1.x), a1);
                a2 = fmaf(c1, u2f_lo(u1.y), a2); a3 = fmaf(c1, u2f_hi(u1.y), a3);
                a0 = fmaf(c2, u2f_lo(u2.x), a0); a1 = fmaf(c2, u2f_hi(u2.x), a1);
                a2 = fmaf(c2, u2f_lo(u2.y), a2); a3 = fmaf(c2, u2f_hi(u2.y), a3);
            }

            const float self = di * di;
            const float o0 = fmaxf(di * a0 + self * u2f_lo(us.x) + bvv.x, 0.0f);
            const float o1 = fmaxf(di * a1 + self * u2f_hi(us.x) + bvv.y, 0.0f);
            const float o2 = fmaxf(di * a2 + self * u2f_lo(us.y) + bvv.z, 0.0f);
            const float o3 = fmaxf(di * a3 + self * u2f_hi(us.y) + bvv.w, 0.0f);
            ushort4 q = {f2bf(o0), f2bf(o1), f2bf(o2), f2bf(o3)};
            *(ushort4*)&As[r][lane * 4] = q;
        }
        __syncthreads();

        // ---- phase 2: GEMM with W2 ----
        f32x16 acc;
        #pragma unroll
        for (int r = 0; r < 16; ++r) acc[r] = 0.f;

        #pragma unroll
        for (int ks = 0; ks < 8; ++ks) {
            U16 ah;
            ah.u = *(const uint4*)&As[l31][ks * 16 + quad8];
            acc = __builtin_amdgcn_mfma_f32_32x32x16_bf16(ah.v, bh[ks].v, acc, 0, 0, 0);
            acc = __builtin_amdgcn_mfma_f32_32x32x16_bf16(ah.v, bl[ks].v, acc, 0, 0, 0);
        }
        __syncthreads();

        #pragma unroll
        for (int reg = 0; reg < 16; ++reg) {
            const int r = (reg & 3) + 8 * (reg >> 2) + 4 * (lane64 >> 5);
            const int rg = row0 + r;
            if (rg < M) outb[(size_t)rg * D + col] = f2bf(acc[reg]);
        }
    }
}

// ============ fused gather (bf16 h), 32-lane group/node, weights inline =========
__global__ __launch_bounds__(256) void k_gather_w(const int* __restrict__ ptr,
                                                  const uint2* __restrict__ csr,
                                                  const float* __restrict__ dinv,
                                                  const unsigned short* __restrict__ h,
                                                  const float* __restrict__ bias,
                                                  const float* __restrict__ res,
                                                  float* __restrict__ outf,
                                                  unsigned short* __restrict__ outb,
                                                  int N) {
    const int g = threadIdx.x >> 5;
    const int lane = threadIdx.x & 31;
    const int i = blockIdx.x * 8 + g;
    if (i >= N) return;

    const int p0 = ptr[i];
    const int p1 = ptr[i + 1];
    const float di = dinv[i];

    const uint2 us = *(const uint2*)(h + (size_t)i * D + lane * 4);
    const float4 bvv = *(const float4*)(bias + lane * 4);

    float a0 = 0.f, a1 = 0.f, a2 = 0.f, a3 = 0.f;
    const unsigned* cb = (const unsigned*)csr;
    int j = p0;
    for (; j + 4 <= p1; j += 4) {
        const uint4 e0 = *(const uint4*)(cb + 2 * (size_t)j);
        const uint4 e1 = *(const uint4*)(cb + 2 * (size_t)j + 4);
        const float c0 = __uint_as_float(e0.y);
        const float c1 = __uint_as_float(e0.w);
        const float c2 = __uint_as_float(e1.y);
        const float c3 = __uint_as_float(e1.w);
        const uint2 u0 = *(const uint2*)(h + (size_t)e0.x * D + lane * 4);
        const uint2 u1 = *(const uint2*)(h + (size_t)e0.z * D + lane * 4);
        const uint2 u2 = *(const uint2*)(h + (size_t)e1.x * D + lane * 4);
        const uint2 u3 = *(const uint2*)(h + (size_t)e1.z * D + lane * 4);
        a0 = fmaf(c0, u2f_lo(u0.x), a0); a1 = fmaf(c0, u2f_hi(u0.x), a1);
        a2 = fmaf(c0, u2f_lo(u0.y), a2); a3 = fmaf(c0, u2f_hi(u0.y), a3);
        a0 = fmaf(c1, u2f_lo(u1.x), a0); a1 = fmaf(c1, u2f_hi(u1.x), a1);
        a2 = fmaf(c1, u2f_lo(u1.y), a2); a3 = fmaf(c1, u2f_hi(u1.y), a3);
        a0 = fmaf(c2, u2f_lo(u2.x), a0); a1 = fmaf(c2, u2f_hi(u2.x), a1);
        a2 = fmaf(c2, u2f_lo(u2.y), a2); a3 = fmaf(c2, u2f_hi(u2.y), a3);
        a0 = fmaf(c3, u2f_lo(u3.x), a0); a1 = fmaf(c3, u2f_hi(u3.x), a1);
        a2 = fmaf(c3, u2f_lo(u3.y), a2); a3 = fmaf(c3, u2f_hi(u3.y), a3);
    }
    const int r = p1 - j;
    if (r > 0) {
        const int j1 = (r > 1) ? j + 1 : j;
        const int j2 = (r > 2) ? j + 2 : j;
        const uint2 e0 = csr[j];
        const uint2 e1 = csr[j1];
        const uint2 e2 = csr[j2];
        const float c0 = __uint_as_float(e0.y);
        const float c1 = (r > 1) ? __uint_as_float(e1.y) : 0.f;
        const float c2 = (r > 2) ? __uint_as_float(e2.y) : 0.f;
        const uint2 u0 = *(const uint2*)(h + (size_t)e0.x * D + lane * 4);
        const uint2 u1 = *(const uint2*)(h + (size_t)e1.x * D + lane * 4);
        const uint2 u2 = *(const uint2*)(h + (size_t)e2.x * D + lane * 4);
        a0 = fmaf(c0, u2f_lo(u0.x), a0); a1 = fmaf(c0, u2f_hi(u0.x), a1);
        a2 = fmaf(c0, u2f_lo(u0.y), a2); a3 = fmaf(c0, u2f_hi(u0.y), a3);
        a0 = fmaf(c1, u2f_lo(u1.x), a0); a1 = fmaf(c1, u2f_hi(u1.x), a1);
        a2 = fmaf(c1, u2f_lo(u1.y), a2); a3 = fmaf(c1, u2f_hi(u1.y), a3);
        a0 = fmaf(c2, u2f_lo(u2.x), a0); a1 = fmaf(c2, u2f_hi(u2.x), a1);
        a2 = fmaf(c2, u2f_lo(u2.y), a2); a3 = fmaf(c2, u2f_hi(u2.y), a3);
    }

    const float self = di * di;
    float o0 = fmaxf(di * a0 + self * u2f_lo(us.x) + bvv.x, 0.0f);
    float o1 = fmaxf(di * a1 + self * u2f_hi(us.x) + bvv.y, 0.0f);
    float o2 = fmaxf(di * a2 + self * u2f_lo(us.y) + bvv.z, 0.0f);
    float o3 = fmaxf(di * a3 + self * u2f_hi(us.y) + bvv.w, 0.0f);
    if (outb) {
        ushort4 q = {f2bf(o0), f2bf(o1), f2bf(o2), f2bf(o3)};
        *(ushort4*)(outb + (size_t)i * D + lane * 4) = q;
    } else {
        const float4 rv = *(const float4*)(res + (size_t)i * D + lane * 4);
        float4 o = {o0 + rv.x, o1 + rv.y, o2 + rv.z, o3 + rv.w};
        *(float4*)(outf + (size_t)i * D + lane * 4) = o;
    }
}

// ===================== launch =====================

extern "C" void kernel_launch(void* const* d_in, const int* in_sizes, int n_in,
                              void* d_out, int out_size, void* d_ws, size_t ws_size,
                              hipStream_t stream) {
    const int N = in_sizes[0] / D;     // 100000
    const int E = in_sizes[1] / 2;     // 600000

    const float* x   = (const float*)d_in[0];
    const int*   ei  = (const int*)d_in[1];
    const int*   src = ei;
    const int*   dst = ei + E;
    const float* W1  = (const float*)d_in[2];
    const float* b1  = (const float*)d_in[3];
    const float* W2  = (const float*)d_in[4];
    const float* b2  = (const float*)d_in[5];
    const float* Wfc = (const float*)d_in[6];
    const float* bfc = (const float*)d_in[7];
    float* out = (float*)d_out;

    // ---- workspace layout ----
    char* ws = (char*)d_ws;
    size_t off = 0;
    auto alloc = [&](size_t bytes) { char* p = ws + off; off += (bytes + 255) & ~(size_t)255; return p; };
    float* dinv    = (float*)alloc((size_t)N * 4);
    int*   cnt     = (int*)  alloc((size_t)N * 4);
    int*   ptr     = (int*)  alloc((size_t)(N + 1) * 4);
    int*   sums    = (int*)  alloc(256 * 4);
    uint2* csr     = (uint2*)alloc((size_t)(E + 64) * sizeof(uint2)); // {src, w}
    unsigned short* W1h = (unsigned short*)alloc(128 * 128 * 2);
    unsigned short* W1l = (unsigned short*)alloc(128 * 128 * 2);
    unsigned short* W2h = (unsigned short*)alloc(128 * 128 * 2);
    unsigned short* W2l = (unsigned short*)alloc(128 * 128 * 2);
    unsigned short* Wfh = (unsigned short*)alloc(128 * 128 * 2);
    unsigned short* Wfl = (unsigned short*)alloc(128 * 128 * 2);
    unsigned short* h   = (unsigned short*)alloc((size_t)N * D * 2);  // bf16 x@W1
    unsigned short* h2  = (unsigned short*)alloc((size_t)N * D * 2);  // bf16 layer-2 pre-agg

    const int nBlk    = (N + 255) / 256;
    const int eBlk    = (E + 255) / 256;
    const int aBlk    = (N + 7) / 8;
    const int nChunks = (N + SCAN_CHUNK - 1) / SCAN_CHUNK;
    const int nTiles  = (N + 31) / 32;
    const int gBlk    = nTiles < 1024 ? nTiles : 1024;   // 512-thr dual: 4 blk/CU = 32 waves
    const int aggBlk  = nTiles < 2048 ? nTiles : 2048;   // 256-thr agg: 8 blk/CU = 32 waves
    const int pBlk    = (nBlk > 192) ? nBlk : 192;

    // ---- weight prep + cnt zero (one dispatch) ----
    k_prep<<<pBlk, 256, 0, stream>>>(W1, W2, Wfc, W1h, W1l, W2h, W2l, Wfh, Wfl, cnt, N);

    // ---- CSR build + dinv (weights inline) ----
    k_hist<<<eBlk, 256, 0, stream>>>(dst, cnt, E);
    k_scan_local<<<nChunks, 256, 0, stream>>>(cnt, ptr, sums, N);
    k_scan_sums<<<1, 256, 0, stream>>>(sums, nChunks);
    k_scan_add<<<nBlk, 256, 0, stream>>>(ptr, sums, cnt, dinv, N, E);
    k_fill<<<eBlk, 256, 0, stream>>>(src, dst, ptr, cnt, dinv, csr, E);

    // ---- h = bf16(x@W1) AND out = x@Wfc + bfc, bf16-A staged once, dbuf ----
    k_gemm_dual<<<gBlk, 512, 0, stream>>>(x, W1h, W1l, Wfh, Wfl, bfc, h, out, N, nTiles);

    // ---- h2 = bf16( relu(A h + b1) @ W2 )  (fused gather#1 + GEMM2) ----
    k_agg_gemm<<<aggBlk, 256, 0, stream>>>(ptr, csr, dinv, h, b1, W2h, W2l, h2, N, nTiles);

    // ---- layer 2 aggregate + residual -> fp32 out ----
    k_gather_w<<<aBlk, 256, 0, stream>>>(ptr, csr, dinv, h2, b2, out, out, nullptr, N);
}

// Round 8
// 279.278 us; speedup vs baseline: 1.1294x; 1.0587x over previous
//
#include <hip/hip_runtime.h>
#include <hip/hip_bf16.h>

#define D 128

typedef __bf16 bf16x8 __attribute__((ext_vector_type(8)));
typedef float f32x16 __attribute__((ext_vector_type(16)));

union U16 { uint4 u; bf16x8 v; };

static __device__ __forceinline__ unsigned short f2bf(float f) {
    unsigned u = __float_as_uint(f);
    unsigned r = (u + 0x7fffu + ((u >> 16) & 1u)) >> 16;   // RNE
    return (unsigned short)r;
}
static __device__ __forceinline__ float bf2f(unsigned short s) {
    return __uint_as_float(((unsigned)s) << 16);
}
static __device__ __forceinline__ float u2f_lo(unsigned x) { return __uint_as_float(x << 16); }
static __device__ __forceinline__ float u2f_hi(unsigned x) { return __uint_as_float(x & 0xffff0000u); }

// 8 FMAs: one full uint4 (8 bf16) against weight c
static __device__ __forceinline__ void fma8(float c, uint4 u,
        float& a0, float& a1, float& a2, float& a3,
        float& a4, float& a5, float& a6, float& a7) {
    a0 = fmaf(c, u2f_lo(u.x), a0); a1 = fmaf(c, u2f_hi(u.x), a1);
    a2 = fmaf(c, u2f_lo(u.y), a2); a3 = fmaf(c, u2f_hi(u.y), a3);
    a4 = fmaf(c, u2f_lo(u.z), a4); a5 = fmaf(c, u2f_hi(u.z), a5);
    a6 = fmaf(c, u2f_lo(u.w), a6); a7 = fmaf(c, u2f_hi(u.w), a7);
}

// ===================== fused weight prep (3 matrices) + cnt zero =====================
__global__ __launch_bounds__(256) void k_prep(
        const float* __restrict__ W1, const float* __restrict__ W2, const float* __restrict__ Wf,
        unsigned short* __restrict__ W1h, unsigned short* __restrict__ W1l,
        unsigned short* __restrict__ W2h, unsigned short* __restrict__ W2l,
        unsigned short* __restrict__ Wfh, unsigned short* __restrict__ Wfl,
        int* __restrict__ cnt, int n) {
    int idx = blockIdx.x * 256 + threadIdx.x;
    if (idx < 3 * 16384) {
        int which = idx >> 14;
        int local = idx & 16383;
        int k = local >> 7, c = local & 127;
        const float* W = (which == 0) ? W1 : (which == 1) ? W2 : Wf;
        unsigned short* Wh = (which == 0) ? W1h : (which == 1) ? W2h : Wfh;
        unsigned short* Wl = (which == 0) ? W1l : (which == 1) ? W2l : Wfl;
        float v = W[k * 128 + c];
        unsigned short h = f2bf(v);
        unsigned short l = f2bf(v - bf2f(h));
        Wh[c * 128 + k] = h;
        Wl[c * 128 + k] = l;
    }
    if (idx < n) cnt[idx] = 0;
}

// ===================== CSR build (counting sort by dst) =====================

__global__ __launch_bounds__(256) void k_hist(const int* __restrict__ dst,
                                              int* __restrict__ cnt, int e) {
    int i = blockIdx.x * 256 + threadIdx.x;
    if (i < e) atomicAdd(&cnt[dst[i]], 1);
}

#define SCAN_CHUNK 1024

__global__ __launch_bounds__(256) void k_scan_local(const int* __restrict__ cnt,
                                                    int* __restrict__ ptr,
                                                    int* __restrict__ sums, int n) {
    __shared__ int tsum[256];
    const int t = threadIdx.x;
    const int base = blockIdx.x * SCAN_CHUNK + t * 4;
    int v[4]; int s = 0;
    #pragma unroll
    for (int i = 0; i < 4; ++i) {
        int idx = base + i;
        v[i] = (idx < n) ? cnt[idx] : 0;
        s += v[i];
    }
    tsum[t] = s;
    __syncthreads();
    for (int off = 1; off < 256; off <<= 1) {
        int x = (t >= off) ? tsum[t - off] : 0;
        __syncthreads();
        tsum[t] += x;
        __syncthreads();
    }
    int run = (t > 0) ? tsum[t - 1] : 0;
    if (t == 255) sums[blockIdx.x] = tsum[255];
    #pragma unroll
    for (int i = 0; i < 4; ++i) {
        int idx = base + i;
        if (idx < n) ptr[idx] = run;
        run += v[i];
    }
}

__global__ __launch_bounds__(256) void k_scan_sums(int* __restrict__ sums, int nChunks) {
    __shared__ int ls[256];
    const int t = threadIdx.x;
    ls[t] = (t < nChunks) ? sums[t] : 0;
    __syncthreads();
    for (int off = 1; off < 256; off <<= 1) {
        int x = (t >= off) ? ls[t - off] : 0;
        __syncthreads();
        ls[t] += x;
        __syncthreads();
    }
    if (t < nChunks) sums[t] = (t > 0) ? ls[t - 1] : 0;
}

__global__ __launch_bounds__(256) void k_scan_add(int* __restrict__ ptr,
                                                  const int* __restrict__ sums,
                                                  int* __restrict__ cnt,
                                                  float* __restrict__ dinv,
                                                  int n, int e) {
    int i = blockIdx.x * 256 + threadIdx.x;
    if (i < n) {
        ptr[i] += sums[i >> 10];
        dinv[i] = rsqrtf((float)(1 + cnt[i]));
        cnt[i] = 0;
    }
    if (i == 0) ptr[n] = e;
}

// store {src, dinv[src]} per edge
__global__ __launch_bounds__(256) void k_fill(const int* __restrict__ src,
                                              const int* __restrict__ dst,
                                              const int* __restrict__ ptr,
                                              int* __restrict__ fill,
                                              const float* __restrict__ dinv,
                                              uint2* __restrict__ csr, int e) {
    int i = blockIdx.x * 256 + threadIdx.x;
    if (i < e) {
        int d = dst[i];
        int s = src[i];
        int slot = ptr[d] + atomicAdd(&fill[d], 1);
        csr[slot] = make_uint2((unsigned)s, __float_as_uint(dinv[s]));
    }
}

// ========== dual-output GEMM, bf16 A (single plane), split-bf16 B, dbuf LDS =====
#define APAD 136   // 128 + 8 bf16 pad: 272 B stride, 16B-aligned

__global__ __launch_bounds__(512, 4) void k_gemm_dual(
        const float* __restrict__ A,
        const unsigned short* __restrict__ B1h, const unsigned short* __restrict__ B1l,
        const unsigned short* __restrict__ B2h, const unsigned short* __restrict__ B2l,
        const float* __restrict__ bias2,
        unsigned short* __restrict__ out1,
        float* __restrict__ out2,
        int M, int nTiles) {
    __shared__ __align__(16) unsigned short As[2][32][APAD];  // [buf][r][c] bf16

    const int tid = threadIdx.x;
    const int wave = tid >> 6;          // 0..7
    const int lane = tid & 63;
    const int l31 = lane & 31;
    const int quad8 = (lane >> 5) * 8;
    const int col = (wave & 3) * 32 + l31;
    const int sel = wave >> 2;          // 0: out1, 1: out2

    const unsigned short* __restrict__ Bh = sel ? B2h : B1h;
    const unsigned short* __restrict__ Bl = sel ? B2l : B1l;

    U16 bh[8], bl[8];
    #pragma unroll
    for (int ks = 0; ks < 8; ++ks) {
        const size_t bo = (size_t)col * D + ks * 16 + quad8;
        bh[ks].u = *(const uint4*)(Bh + bo);
        bl[ks].u = *(const uint4*)(Bl + bo);
    }
    const float bv = bias2[col];

    // per-thread fixed staging coordinates (2 float4 over [32][32])
    const int r0 = tid >> 5;            // 0..15
    const int c0 = (tid & 31) * 4;
    const int r1 = r0 + 16;             // 16..31

    int t = blockIdx.x;
    float4 v0, v1;
    if (t < nTiles) {
        int rg0 = t * 32 + r0; if (rg0 >= M) rg0 = M - 1;
        int rg1 = t * 32 + r1; if (rg1 >= M) rg1 = M - 1;
        v0 = *(const float4*)(A + (size_t)rg0 * D + c0);
        v1 = *(const float4*)(A + (size_t)rg1 * D + c0);
    }
    int cur = 0;

    while (t < nTiles) {
        const int row0 = t * 32;

        // convert current regs -> LDS[cur] (plain bf16)
        {
            ushort4 hq;
            hq.x = f2bf(v0.x); hq.y = f2bf(v0.y); hq.z = f2bf(v0.z); hq.w = f2bf(v0.w);
            *(ushort4*)&As[cur][r0][c0] = hq;
            hq.x = f2bf(v1.x); hq.y = f2bf(v1.y); hq.z = f2bf(v1.z); hq.w = f2bf(v1.w);
            *(ushort4*)&As[cur][r1][c0] = hq;
        }

        // issue next tile's loads (latency hides under MFMA + stores)
        const int tn = t + gridDim.x;
        if (tn < nTiles) {
            int rg0 = tn * 32 + r0; if (rg0 >= M) rg0 = M - 1;
            int rg1 = tn * 32 + r1; if (rg1 >= M) rg1 = M - 1;
            v0 = *(const float4*)(A + (size_t)rg0 * D + c0);
            v1 = *(const float4*)(A + (size_t)rg1 * D + c0);
        }

        __syncthreads();

        f32x16 acc;
        #pragma unroll
        for (int r = 0; r < 16; ++r) acc[r] = 0.f;

        #pragma unroll
        for (int ks = 0; ks < 8; ++ks) {
            U16 ah;
            ah.u = *(const uint4*)&As[cur][l31][ks * 16 + quad8];
            acc = __builtin_amdgcn_mfma_f32_32x32x16_bf16(ah.v, bh[ks].v, acc, 0, 0, 0);
            acc = __builtin_amdgcn_mfma_f32_32x32x16_bf16(ah.v, bl[ks].v, acc, 0, 0, 0);
        }

        if (sel == 0) {
            #pragma unroll
            for (int reg = 0; reg < 16; ++reg) {
                const int r = (reg & 3) + 8 * (reg >> 2) + 4 * (lane >> 5);
                const int rg = row0 + r;
                if (rg < M) out1[(size_t)rg * D + col] = f2bf(acc[reg]);
            }
        } else {
            #pragma unroll
            for (int reg = 0; reg < 16; ++reg) {
                const int r = (reg & 3) + 8 * (reg >> 2) + 4 * (lane >> 5);
                const int rg = row0 + r;
                if (rg < M) out2[(size_t)rg * D + col] = acc[reg] + bv;
            }
        }

        cur ^= 1;
        t = tn;
    }
}

// ========== fused aggregate(layer1) + GEMM(W2): h2 = bf16(relu(A h + b1) @ W2) ==
// Phase 1: 16 sixteen-lane groups, 2 rows each (uint4 = full row per load instr).
// Phase 2: 4 waves, register-resident split-bf16 W2, 2 MFMA per k-step.
__global__ __launch_bounds__(256, 4) void k_agg_gemm(
        const int* __restrict__ ptr,
        const uint2* __restrict__ csr,
        const float* __restrict__ dinv,
        const unsigned short* __restrict__ h,
        const float* __restrict__ bias,
        const unsigned short* __restrict__ Bh, const unsigned short* __restrict__ Bl,
        unsigned short* __restrict__ outb,
        int M, int nTiles) {
    __shared__ __align__(16) unsigned short As[32][APAD];

    const int tid = threadIdx.x;
    const int wave = tid >> 6;
    const int lane64 = tid & 63;
    const int l31 = lane64 & 31;
    const int quad8 = (lane64 >> 5) * 8;
    const int col = wave * 32 + l31;

    const int g16 = tid >> 4;           // 0..15 aggregation group
    const int l16 = tid & 15;           // lane within group: 8 dims each

    U16 bh[8], bl[8];
    #pragma unroll
    for (int ks = 0; ks < 8; ++ks) {
        const size_t bo = (size_t)col * D + ks * 16 + quad8;
        bh[ks].u = *(const uint4*)(Bh + bo);
        bl[ks].u = *(const uint4*)(Bl + bo);
    }
    const float4 bv0 = *(const float4*)(bias + l16 * 8);
    const float4 bv1 = *(const float4*)(bias + l16 * 8 + 4);
    const unsigned* cb = (const unsigned*)csr;

    for (int t = blockIdx.x; t < nTiles; t += gridDim.x) {
        const int row0 = t * 32;

        // ---- phase 1: aggregate rows g16*2, g16*2+1 into LDS ----
        for (int rr = 0; rr < 2; ++rr) {
            const int r = g16 * 2 + rr;
            int ig = row0 + r; if (ig >= M) ig = M - 1;
            const int p0 = ptr[ig];
            const int p1 = ptr[ig + 1];
            const float di = dinv[ig];
            const uint4 us = *(const uint4*)(h + (size_t)ig * D + l16 * 8);

            float a0=0.f,a1=0.f,a2=0.f,a3=0.f,a4=0.f,a5=0.f,a6=0.f,a7=0.f;
            int j = p0;
            for (; j + 4 <= p1; j += 4) {
                const uint4 e0 = *(const uint4*)(cb + 2 * (size_t)j);
                const uint4 e1 = *(const uint4*)(cb + 2 * (size_t)j + 4);
                const float c0 = __uint_as_float(e0.y);
                const float c1 = __uint_as_float(e0.w);
                const float c2 = __uint_as_float(e1.y);
                const float c3 = __uint_as_float(e1.w);
                const uint4 u0 = *(const uint4*)(h + (size_t)e0.x * D + l16 * 8);
                const uint4 u1 = *(const uint4*)(h + (size_t)e0.z * D + l16 * 8);
                const uint4 u2 = *(const uint4*)(h + (size_t)e1.x * D + l16 * 8);
                const uint4 u3 = *(const uint4*)(h + (size_t)e1.z * D + l16 * 8);
                fma8(c0, u0, a0,a1,a2,a3,a4,a5,a6,a7);
                fma8(c1, u1, a0,a1,a2,a3,a4,a5,a6,a7);
                fma8(c2, u2, a0,a1,a2,a3,a4,a5,a6,a7);
                fma8(c3, u3, a0,a1,a2,a3,a4,a5,a6,a7);
            }
            const int rem = p1 - j;
            if (rem > 0) {
                const int j1 = (rem > 1) ? j + 1 : j;
                const int j2 = (rem > 2) ? j + 2 : j;
                const uint2 e0 = csr[j];
                const uint2 e1 = csr[j1];
                const uint2 e2 = csr[j2];
                const float c0 = __uint_as_float(e0.y);
                const float c1 = (rem > 1) ? __uint_as_float(e1.y) : 0.f;
                const float c2 = (rem > 2) ? __uint_as_float(e2.y) : 0.f;
                const uint4 u0 = *(const uint4*)(h + (size_t)e0.x * D + l16 * 8);
                const uint4 u1 = *(const uint4*)(h + (size_t)e1.x * D + l16 * 8);
                const uint4 u2 = *(const uint4*)(h + (size_t)e2.x * D + l16 * 8);
                fma8(c0, u0, a0,a1,a2,a3,a4,a5,a6,a7);
                fma8(c1, u1, a0,a1,a2,a3,a4,a5,a6,a7);
                fma8(c2, u2, a0,a1,a2,a3,a4,a5,a6,a7);
            }

            const float self = di * di;
            const float o0 = fmaxf(di * a0 + self * u2f_lo(us.x) + bv0.x, 0.0f);
            const float o1 = fmaxf(di * a1 + self * u2f_hi(us.x) + bv0.y, 0.0f);
            const float o2 = fmaxf(di * a2 + self * u2f_lo(us.y) + bv0.z, 0.0f);
            const float o3 = fmaxf(di * a3 + self * u2f_hi(us.y) + bv0.w, 0.0f);
            const float o4 = fmaxf(di * a4 + self * u2f_lo(us.z) + bv1.x, 0.0f);
            const float o5 = fmaxf(di * a5 + self * u2f_hi(us.z) + bv1.y, 0.0f);
            const float o6 = fmaxf(di * a6 + self * u2f_lo(us.w) + bv1.z, 0.0f);
            const float o7 = fmaxf(di * a7 + self * u2f_hi(us.w) + bv1.w, 0.0f);
            ushort4 q0 = {f2bf(o0), f2bf(o1), f2bf(o2), f2bf(o3)};
            ushort4 q1 = {f2bf(o4), f2bf(o5), f2bf(o6), f2bf(o7)};
            *(ushort4*)&As[r][l16 * 8] = q0;
            *(ushort4*)&As[r][l16 * 8 + 4] = q1;
        }
        __syncthreads();

        // ---- phase 2: GEMM with W2 ----
        f32x16 acc;
        #pragma unroll
        for (int r = 0; r < 16; ++r) acc[r] = 0.f;

        #pragma unroll
        for (int ks = 0; ks < 8; ++ks) {
            U16 ah;
            ah.u = *(const uint4*)&As[l31][ks * 16 + quad8];
            acc = __builtin_amdgcn_mfma_f32_32x32x16_bf16(ah.v, bh[ks].v, acc, 0, 0, 0);
            acc = __builtin_amdgcn_mfma_f32_32x32x16_bf16(ah.v, bl[ks].v, acc, 0, 0, 0);
        }
        __syncthreads();

        #pragma unroll
        for (int reg = 0; reg < 16; ++reg) {
            const int r = (reg & 3) + 8 * (reg >> 2) + 4 * (lane64 >> 5);
            const int rg = row0 + r;
            if (rg < M) outb[(size_t)rg * D + col] = f2bf(acc[reg]);
        }
    }
}

// ============ fused gather (bf16 h), 16-lane group/node, weights inline =========
__global__ __launch_bounds__(256) void k_gather_w(const int* __restrict__ ptr,
                                                  const uint2* __restrict__ csr,
                                                  const float* __restrict__ dinv,
                                                  const unsigned short* __restrict__ h,
                                                  const float* __restrict__ bias,
                                                  const float* __restrict__ res,
                                                  float* __restrict__ outf,
                                                  unsigned short* __restrict__ outb,
                                                  int N) {
    const int g = threadIdx.x >> 4;     // 0..15
    const int lane = threadIdx.x & 15;  // 8 dims each
    const int i = blockIdx.x * 16 + g;
    if (i >= N) return;

    const int p0 = ptr[i];
    const int p1 = ptr[i + 1];
    const float di = dinv[i];

    const uint4 us = *(const uint4*)(h + (size_t)i * D + lane * 8);
    const float4 bv0 = *(const float4*)(bias + lane * 8);
    const float4 bv1 = *(const float4*)(bias + lane * 8 + 4);

    float a0=0.f,a1=0.f,a2=0.f,a3=0.f,a4=0.f,a5=0.f,a6=0.f,a7=0.f;
    const unsigned* cb = (const unsigned*)csr;
    int j = p0;
    for (; j + 4 <= p1; j += 4) {
        const uint4 e0 = *(const uint4*)(cb + 2 * (size_t)j);
        const uint4 e1 = *(const uint4*)(cb + 2 * (size_t)j + 4);
        const float c0 = __uint_as_float(e0.y);
        const float c1 = __uint_as_float(e0.w);
        const float c2 = __uint_as_float(e1.y);
        const float c3 = __uint_as_float(e1.w);
        const uint4 u0 = *(const uint4*)(h + (size_t)e0.x * D + lane * 8);
        const uint4 u1 = *(const uint4*)(h + (size_t)e0.z * D + lane * 8);
        const uint4 u2 = *(const uint4*)(h + (size_t)e1.x * D + lane * 8);
        const uint4 u3 = *(const uint4*)(h + (size_t)e1.z * D + lane * 8);
        fma8(c0, u0, a0,a1,a2,a3,a4,a5,a6,a7);
        fma8(c1, u1, a0,a1,a2,a3,a4,a5,a6,a7);
        fma8(c2, u2, a0,a1,a2,a3,a4,a5,a6,a7);
        fma8(c3, u3, a0,a1,a2,a3,a4,a5,a6,a7);
    }
    const int rem = p1 - j;
    if (rem > 0) {
        const int j1 = (rem > 1) ? j + 1 : j;
        const int j2 = (rem > 2) ? j + 2 : j;
        const uint2 e0 = csr[j];
        const uint2 e1 = csr[j1];
        const uint2 e2 = csr[j2];
        const float c0 = __uint_as_float(e0.y);
        const float c1 = (rem > 1) ? __uint_as_float(e1.y) : 0.f;
        const float c2 = (rem > 2) ? __uint_as_float(e2.y) : 0.f;
        const uint4 u0 = *(const uint4*)(h + (size_t)e0.x * D + lane * 8);
        const uint4 u1 = *(const uint4*)(h + (size_t)e1.x * D + lane * 8);
        const uint4 u2 = *(const uint4*)(h + (size_t)e2.x * D + lane * 8);
        fma8(c0, u0, a0,a1,a2,a3,a4,a5,a6,a7);
        fma8(c1, u1, a0,a1,a2,a3,a4,a5,a6,a7);
        fma8(c2, u2, a0,a1,a2,a3,a4,a5,a6,a7);
    }

    const float self = di * di;
    float o0 = fmaxf(di * a0 + self * u2f_lo(us.x) + bv0.x, 0.0f);
    float o1 = fmaxf(di * a1 + self * u2f_hi(us.x) + bv0.y, 0.0f);
    float o2 = fmaxf(di * a2 + self * u2f_lo(us.y) + bv0.z, 0.0f);
    float o3 = fmaxf(di * a3 + self * u2f_hi(us.y) + bv0.w, 0.0f);
    float o4 = fmaxf(di * a4 + self * u2f_lo(us.z) + bv1.x, 0.0f);
    float o5 = fmaxf(di * a5 + self * u2f_hi(us.z) + bv1.y, 0.0f);
    float o6 = fmaxf(di * a6 + self * u2f_lo(us.w) + bv1.z, 0.0f);
    float o7 = fmaxf(di * a7 + self * u2f_hi(us.w) + bv1.w, 0.0f);
    if (outb) {
        ushort4 q0 = {f2bf(o0), f2bf(o1), f2bf(o2), f2bf(o3)};
        ushort4 q1 = {f2bf(o4), f2bf(o5), f2bf(o6), f2bf(o7)};
        *(ushort4*)(outb + (size_t)i * D + lane * 8) = q0;
        *(ushort4*)(outb + (size_t)i * D + lane * 8 + 4) = q1;
    } else {
        const float4 rv0 = *(const float4*)(res + (size_t)i * D + lane * 8);
        const float4 rv1 = *(const float4*)(res + (size_t)i * D + lane * 8 + 4);
        float4 w0 = {o0 + rv0.x, o1 + rv0.y, o2 + rv0.z, o3 + rv0.w};
        float4 w1 = {o4 + rv1.x, o5 + rv1.y, o6 + rv1.z, o7 + rv1.w};
        *(float4*)(outf + (size_t)i * D + lane * 8) = w0;
        *(float4*)(outf + (size_t)i * D + lane * 8 + 4) = w1;
    }
}

// ===================== launch =====================

extern "C" void kernel_launch(void* const* d_in, const int* in_sizes, int n_in,
                              void* d_out, int out_size, void* d_ws, size_t ws_size,
                              hipStream_t stream) {
    const int N = in_sizes[0] / D;     // 100000
    const int E = in_sizes[1] / 2;     // 600000

    const float* x   = (const float*)d_in[0];
    const int*   ei  = (const int*)d_in[1];
    const int*   src = ei;
    const int*   dst = ei + E;
    const float* W1  = (const float*)d_in[2];
    const float* b1  = (const float*)d_in[3];
    const float* W2  = (const float*)d_in[4];
    const float* b2  = (const float*)d_in[5];
    const float* Wfc = (const float*)d_in[6];
    const float* bfc = (const float*)d_in[7];
    float* out = (float*)d_out;

    // ---- workspace layout ----
    char* ws = (char*)d_ws;
    size_t off = 0;
    auto alloc = [&](size_t bytes) { char* p = ws + off; off += (bytes + 255) & ~(size_t)255; return p; };
    float* dinv    = (float*)alloc((size_t)N * 4);
    int*   cnt     = (int*)  alloc((size_t)N * 4);
    int*   ptr     = (int*)  alloc((size_t)(N + 1) * 4);
    int*   sums    = (int*)  alloc(256 * 4);
    uint2* csr     = (uint2*)alloc((size_t)(E + 64) * sizeof(uint2)); // {src, w}
    unsigned short* W1h = (unsigned short*)alloc(128 * 128 * 2);
    unsigned short* W1l = (unsigned short*)alloc(128 * 128 * 2);
    unsigned short* W2h = (unsigned short*)alloc(128 * 128 * 2);
    unsigned short* W2l = (unsigned short*)alloc(128 * 128 * 2);
    unsigned short* Wfh = (unsigned short*)alloc(128 * 128 * 2);
    unsigned short* Wfl = (unsigned short*)alloc(128 * 128 * 2);
    unsigned short* h   = (unsigned short*)alloc((size_t)N * D * 2);  // bf16 x@W1
    unsigned short* h2  = (unsigned short*)alloc((size_t)N * D * 2);  // bf16 layer-2 pre-agg

    const int nBlk    = (N + 255) / 256;
    const int eBlk    = (E + 255) / 256;
    const int aBlk    = (N + 15) / 16;                   // 16 nodes/block (16-lane groups)
    const int nChunks = (N + SCAN_CHUNK - 1) / SCAN_CHUNK;
    const int nTiles  = (N + 31) / 32;
    const int gBlk    = nTiles < 1024 ? nTiles : 1024;
    const int aggBlk  = nTiles < 1024 ? nTiles : 1024;   // 1024 measured-best (r5 vs r7)
    const int pBlk    = (nBlk > 192) ? nBlk : 192;

    // ---- weight prep + cnt zero (one dispatch) ----
    k_prep<<<pBlk, 256, 0, stream>>>(W1, W2, Wfc, W1h, W1l, W2h, W2l, Wfh, Wfl, cnt, N);

    // ---- CSR build + dinv (weights inline) ----
    k_hist<<<eBlk, 256, 0, stream>>>(dst, cnt, E);
    k_scan_local<<<nChunks, 256, 0, stream>>>(cnt, ptr, sums, N);
    k_scan_sums<<<1, 256, 0, stream>>>(sums, nChunks);
    k_scan_add<<<nBlk, 256, 0, stream>>>(ptr, sums, cnt, dinv, N, E);
    k_fill<<<eBlk, 256, 0, stream>>>(src, dst, ptr, cnt, dinv, csr, E);

    // ---- h = bf16(x@W1) AND out = x@Wfc + bfc, bf16-A staged once, dbuf ----
    k_gemm_dual<<<gBlk, 512, 0, stream>>>(x, W1h, W1l, Wfh, Wfl, bfc, h, out, N, nTiles);

    // ---- h2 = bf16( relu(A h + b1) @ W2 )  (fused gather#1 + GEMM2) ----
    k_agg_gemm<<<aggBlk, 256, 0, stream>>>(ptr, csr, dinv, h, b1, W2h, W2l, h2, N, nTiles);

    // ---- layer 2 aggregate + residual -> fp32 out ----
    k_gather_w<<<aBlk, 256, 0, stream>>>(ptr, csr, dinv, h2, b2, out, out, nullptr, N);
}